// Round 6
// baseline (100.603 us; speedup 1.0000x reference)
//
#include <hip/hip_runtime.h>
#include <math.h>

#define NN 8192
#define DD 256
#define MARGIN 0.2f
#define SL 8                 // candidate slices (grid.x)
#define CPS (NN / SL)        // 1024 candidates per slice
#define TILES (CPS / 128)    // 8 tiles per block
#define NSTEP (TILES * 4)    // 32 k-steps (BK=32)
#define IMAX 0x7fffffff

typedef __attribute__((ext_vector_type(8))) short bf16x8;  // 8 bf16 (4 VGPRs)
typedef __attribute__((ext_vector_type(4))) float f32x4;
typedef unsigned int u32;
typedef unsigned short u16;

static __device__ __forceinline__ u16 f2bf(float f) {   // RNE fp32 -> bf16
    u32 u = __float_as_uint(f);
    return (u16)((u + 0x7fffu + ((u >> 16) & 1u)) >> 16);
}

static __device__ __forceinline__ void gload16(const void* g, void* l) {
    __builtin_amdgcn_global_load_lds((const __attribute__((address_space(1))) void*)g,
                                     (__attribute__((address_space(3))) void*)l, 16, 0, 0);
}

// ---------- kernel 1: norms + normalized bf16 matrix ----------
__global__ void kprep(const float* __restrict__ emb, u16* __restrict__ ENb,
                      float* __restrict__ invn) {
    const int wid = threadIdx.x >> 6, l = threadIdx.x & 63;
    const int row = blockIdx.x * 4 + wid;
    const float4 v = *(const float4*)&emb[(size_t)row * DD + l * 4];
    float ss = v.x * v.x + v.y * v.y + v.z * v.z + v.w * v.w;
#pragma unroll
    for (int o = 1; o < 64; o <<= 1) ss += __shfl_xor(ss, o);
    const float inv = 1.0f / fmaxf(sqrtf(ss), 1e-12f);
    if (l == 0) invn[row] = inv;
    ushort4 o4;
    o4.x = f2bf(v.x * inv); o4.y = f2bf(v.y * inv);
    o4.z = f2bf(v.z * inv); o4.w = f2bf(v.w * inv);
    *(ushort4*)&ENb[(size_t)row * DD + l * 4] = o4;
}

// ---------- kernel 2: first two indices of each class -> posidx ----------
static __device__ __forceinline__ void comb2(int& a1, int& a2, int b1, int b2) {
    const int lo = min(a1, b1);
    const int hi = max(a1, b1);
    a2 = min(hi, min(a2, b2));
    a1 = lo;
}

__global__ void kclass(const int* __restrict__ labels, int* __restrict__ posidx) {
    const int c = blockIdx.x;       // one block per class
    const int tid = threadIdx.x;    // 256
    int m1 = IMAX, m2 = IMAX;
    for (int j = tid; j < NN; j += 256) {   // ascending -> m1 < m2 per thread
        if (labels[j] == c) {
            if (m1 == IMAX) m1 = j;
            else if (m2 == IMAX) m2 = j;
        }
    }
#pragma unroll
    for (int o = 1; o < 64; o <<= 1)
        comb2(m1, m2, __shfl_xor(m1, o), __shfl_xor(m2, o));
    __shared__ int s1[4], s2[4];
    __shared__ int bj1, bj2;
    const int wave = tid >> 6, lane = tid & 63;
    if (lane == 0) { s1[wave] = m1; s2[wave] = m2; }
    __syncthreads();
    if (tid == 0) {
        comb2(m1, m2, s1[1], s2[1]);
        comb2(m1, m2, s1[2], s2[2]);
        comb2(m1, m2, s1[3], s2[3]);
        bj1 = m1; bj2 = m2;
    }
    __syncthreads();
    const int j1 = bj1, j2 = bj2;
    for (int j = tid; j < NN; j += 256)     // every j has exactly one class
        if (labels[j] == c) posidx[j] = (j2 == IMAX) ? -1 : ((j == j1) ? j2 : j1);
}

// ---------- kernel 3: exact fp32 d_ap ----------
__global__ void kdap(const float* __restrict__ emb, const float* __restrict__ invn,
                     const int* __restrict__ posidx, float* __restrict__ dap) {
    const int wid = threadIdx.x >> 6, l = threadIdx.x & 63;
    const int i = blockIdx.x * 4 + wid;
    const int p = posidx[i];
    float dv = 0.0f;
    if (p >= 0) {   // uniform per wave
        const float4 a = *(const float4*)&emb[(size_t)i * DD + l * 4];
        const float4 b = *(const float4*)&emb[(size_t)p * DD + l * 4];
        float s = a.x * b.x + a.y * b.y + a.z * b.z + a.w * b.w;
#pragma unroll
        for (int o = 1; o < 64; o <<= 1) s += __shfl_xor(s, o);
        const float sim = s * invn[i] * invn[p];
        dv = fminf(fmaxf(1.0f - sim, 0.0f), 2.0f);
    }
    if (l == 0) dap[i] = dv;
}

// ---------- kernel 4: MFMA mining — counted-vmcnt 4-buffer pipeline ----------
// B (anchor tile) staged ONCE into 4 LDS buffers (one per kc); A (candidates)
// flows through a 4-buffer depth-3 pipeline with s_waitcnt vmcnt(6) (never 0
// in steady state) and raw s_barriers — loads stay in flight across barriers.
__global__ __launch_bounds__(256, 2) void kmine(
    const u16* __restrict__ ENb, const int* __restrict__ labels,
    const float* __restrict__ dap, float* __restrict__ pM1, float* __restrict__ pMN)
{
    __shared__ __align__(16) u16 As[4][128 * 32];   // A pipeline buffers (8 KB each)
    __shared__ __align__(16) u16 Bs[4][128 * 32];   // B kc-chunks (staged once)
    __shared__ __align__(16) int Ls[CPS];           // candidate labels (4 KB)
    __shared__ float RedN[2][128], RedS[2][128];

    const int tid = threadIdx.x;
    const int l = tid & 63;
    const int wid = tid >> 6;
    const int wr = wid >> 1;      // candidate half (M)
    const int wc = wid & 1;       // anchor half (N)
    const int slice = blockIdx.x;
    const int a0 = blockIdx.y * 128;

    const int frow = l & 15;      // row within 16x16 subtile
    const int fq = l >> 4;        // k-quarter 0..3

    // --- prologue vmem, in a fixed order so static vmcnt counts hold ---
    // (1) candidate labels (1 op)  (2) per-anchor consts (8 ops)
    const int4 lv = *(const int4*)&labels[slice * CPS + tid * 4];
    int la[4]; float hiv[4];
#pragma unroll
    for (int n = 0; n < 4; ++n) {
        const int ai = a0 + wc * 64 + n * 16 + frow;
        la[n] = labels[ai];
        hiv[n] = 1.0f - dap[ai];
    }
    *(int4*)&Ls[tid * 4] = lv;    // ds_write (compiler waits on label load only)

    // (3) stage all B kc-chunks and first 3 A buffers
    const char* ENc = (const char*)ENb;
    const char* agp = ENc + (size_t)(slice * CPS + (tid >> 2)) * 512 + (tid & 3) * 16;
    const char* bgp = ENc + (size_t)(a0 + (tid >> 2)) * 512 + (tid & 3) * 16;

#define STAGE_A(b, off) do {                                  \
        gload16(agp + (off),         &As[b][tid * 8]);        \
        gload16(agp + (off) + 32768, &As[b][tid * 8 + 2048]); \
    } while (0)
#define STAGE_B(b, off) do {                                  \
        gload16(bgp + (off),         &Bs[b][tid * 8]);        \
        gload16(bgp + (off) + 32768, &Bs[b][tid * 8 + 2048]); \
    } while (0)

    STAGE_B(0, 0); STAGE_B(1, 64); STAGE_B(2, 128); STAGE_B(3, 192);
    STAGE_A(0, 0); STAGE_A(1, 64); STAGE_A(2, 128);

    asm volatile("s_waitcnt lgkmcnt(0)" ::: "memory");   // labels visible
    __builtin_amdgcn_s_barrier();

    float mN[4], m1[4];
#pragma unroll
    for (int n = 0; n < 4; ++n) { mN[n] = -INFINITY; m1[n] = -INFINITY; }

    const f32x4 Zv = {0.f, 0.f, 0.f, 0.f};
    f32x4 acc[4][4];

#pragma unroll
    for (int s = 0; s < NSTEP; ++s) {
        const int b = s & 3;
        const int t = s >> 2;
        // issue stage(s+3): overwrites buffer computed at s-1 (freed by its
        // trailing barrier); 2 loads -> steady-state 6 outstanding
        if (s + 3 < NSTEP) {
            const int s3 = s + 3;
            STAGE_A(s3 & 3, (s3 >> 2) * 65536 + (s3 & 3) * 64);
        }
        // counted wait: stage(s) (and B, first time) landed; 3 stages in flight
        if (s <= NSTEP - 4)      asm volatile("s_waitcnt vmcnt(6)" ::: "memory");
        else if (s == NSTEP - 3) asm volatile("s_waitcnt vmcnt(4)" ::: "memory");
        else if (s == NSTEP - 2) asm volatile("s_waitcnt vmcnt(2)" ::: "memory");
        else                     asm volatile("s_waitcnt vmcnt(0)" ::: "memory");
        __builtin_amdgcn_s_barrier();   // all waves' stage(s) visible

        // fragments: 64 lanes read 64 distinct 16B chunks of a 1KB region -> conflict-free
        bf16x8 af[4], bf[4];
#pragma unroll
        for (int m = 0; m < 4; ++m)
            af[m] = *(const bf16x8*)&As[b][(wr * 64 + m * 16 + frow) * 32 + fq * 8];
#pragma unroll
        for (int n = 0; n < 4; ++n)
            bf[n] = *(const bf16x8*)&Bs[b][(wc * 64 + n * 16 + frow) * 32 + fq * 8];

        __builtin_amdgcn_s_setprio(1);
        if (b == 0) {
#pragma unroll
            for (int m = 0; m < 4; ++m)
#pragma unroll
                for (int n = 0; n < 4; ++n)
                    acc[m][n] = __builtin_amdgcn_mfma_f32_16x16x32_bf16(
                        af[m], bf[n], Zv, 0, 0, 0);          // fresh tile: C = 0
        } else {
#pragma unroll
            for (int m = 0; m < 4; ++m)
#pragma unroll
                for (int n = 0; n < 4; ++n)
                    acc[m][n] = __builtin_amdgcn_mfma_f32_16x16x32_bf16(
                        af[m], bf[n], acc[m][n], 0, 0, 0);
        }
        __builtin_amdgcn_s_setprio(0);

        if (b == 3) {   // tile epilogue: mask + running maxes
            int lcv[16];
#pragma unroll
            for (int m = 0; m < 4; ++m) {
                const int4 v = *(const int4*)&Ls[t * 128 + wr * 64 + m * 16 + fq * 4];
                lcv[m * 4 + 0] = v.x; lcv[m * 4 + 1] = v.y;
                lcv[m * 4 + 2] = v.z; lcv[m * 4 + 3] = v.w;
            }
#pragma unroll
            for (int n = 0; n < 4; ++n) {
#pragma unroll
                for (int m = 0; m < 4; ++m)
#pragma unroll
                    for (int r = 0; r < 4; ++r) {
                        const float sv = acc[m][n][r];
                        const float sel = (lcv[m * 4 + r] != la[n]) ? sv : -INFINITY;
                        mN[n] = fmaxf(mN[n], sel);
                        m1[n] = fmaxf(m1[n], (sel < hiv[n]) ? sel : -INFINITY);
                    }
            }
        }
        __builtin_amdgcn_s_barrier();   // frees As[b] for overwrite next step
    }
#undef STAGE_A
#undef STAGE_B

    // reduce the 4 candidate row-groups (lanes l, l^16, l^32, l^48 share anchor)
#pragma unroll
    for (int n = 0; n < 4; ++n) {
        mN[n] = fmaxf(mN[n], __shfl_xor(mN[n], 16));
        mN[n] = fmaxf(mN[n], __shfl_xor(mN[n], 32));
        m1[n] = fmaxf(m1[n], __shfl_xor(m1[n], 16));
        m1[n] = fmaxf(m1[n], __shfl_xor(m1[n], 32));
    }
    if (fq == 0) {
#pragma unroll
        for (int n = 0; n < 4; ++n) {
            RedN[wr][wc * 64 + n * 16 + frow] = mN[n];
            RedS[wr][wc * 64 + n * 16 + frow] = m1[n];
        }
    }
    __syncthreads();
    if (tid < 128) {   // combine the two candidate halves, write partials
        pMN[slice * NN + a0 + tid] = fmaxf(RedN[0][tid], RedN[1][tid]);
        pM1[slice * NN + a0 + tid] = fmaxf(RedS[0][tid], RedS[1][tid]);
    }
}

// ---------- kernel 5: combine slices -> per-block partial sums ----------
__global__ void kcombine(const int* __restrict__ posidx, const float* __restrict__ dap,
                         const float* __restrict__ pM1, const float* __restrict__ pMN,
                         float* __restrict__ partials)
{
    const int i = blockIdx.x * 256 + threadIdx.x;
    float loss = 0.0f, cnt = 0.0f;
    if (posidx[i] >= 0) {
        float s1 = -INFINITY, sN = -INFINITY;
#pragma unroll
        for (int s = 0; s < SL; ++s) {
            s1 = fmaxf(s1, pM1[s * NN + i]);
            sN = fmaxf(sN, pMN[s * NN + i]);
        }
        const float da = dap[i];
        const float lo = 1.0f - da - MARGIN;
        const float M = (s1 > lo) ? s1 : sN;   // has_semi ? best semi : hardest
        const float dan = fminf(fmaxf(1.0f - M, 0.0f), 2.0f);
        loss = fmaxf(da - dan + MARGIN, 0.0f);
        cnt = 1.0f;
    }
#pragma unroll
    for (int off = 1; off < 64; off <<= 1) {
        loss += __shfl_xor(loss, off);
        cnt  += __shfl_xor(cnt, off);
    }
    __shared__ float sl[4], sc[4];
    const int wave = threadIdx.x >> 6, lane = threadIdx.x & 63;
    if (lane == 0) { sl[wave] = loss; sc[wave] = cnt; }
    __syncthreads();
    if (threadIdx.x == 0) {
        partials[blockIdx.x]      = sl[0] + sl[1] + sl[2] + sl[3];
        partials[32 + blockIdx.x] = sc[0] + sc[1] + sc[2] + sc[3];
    }
}

// ---------- kernel 6: final scalar ----------
__global__ void kfinal(const float* __restrict__ partials, float* __restrict__ out) {
    const int t = threadIdx.x;  // 64
    float L = (t < 32) ? partials[t] : 0.0f;
    float C = (t < 32) ? partials[32 + t] : 0.0f;
#pragma unroll
    for (int off = 1; off < 64; off <<= 1) {
        L += __shfl_xor(L, off);
        C += __shfl_xor(C, off);
    }
    if (t == 0) out[0] = (C > 0.0f) ? (L / C) : 0.0f;
}

extern "C" void kernel_launch(void* const* d_in, const int* in_sizes, int n_in,
                              void* d_out, int out_size, void* d_ws, size_t ws_size,
                              hipStream_t stream) {
    const float* emb  = (const float*)d_in[0];
    const int* labels = (const int*)d_in[1];
    float* out = (float*)d_out;

    char* w = (char*)d_ws;
    u16*   ENb  = (u16*)w;                       w += (size_t)NN * DD * 2;   // 4 MB
    float* invn = (float*)w;                     w += NN * 4;
    float* dapv = (float*)w;                     w += NN * 4;
    int*   posi = (int*)w;                       w += NN * 4;
    float* pM1  = (float*)w;                     w += (size_t)SL * NN * 4;   // 256 KB
    float* pMN  = (float*)w;                     w += (size_t)SL * NN * 4;   // 256 KB
    float* parts = (float*)w;

    kprep<<<NN / 4, 256, 0, stream>>>(emb, ENb, invn);
    kclass<<<128, 256, 0, stream>>>(labels, posi);
    kdap<<<NN / 4, 256, 0, stream>>>(emb, invn, posi, dapv);
    kmine<<<dim3(SL, NN / 128), 256, 0, stream>>>(ENb, labels, dapv, pM1, pMN);
    kcombine<<<NN / 256, 256, 0, stream>>>(posi, dapv, pM1, pMN, parts);
    kfinal<<<1, 64, 0, stream>>>(parts, out);
}

// Round 7
// 70.992 us; speedup vs baseline: 1.4171x; 1.4171x over previous
//
#include <hip/hip_runtime.h>
#include <math.h>

#define NN 8192
#define DD 256
#define MARGIN 0.2f
#define SL 8                 // candidate slices (grid.x)
#define CPS (NN / SL)        // 1024 candidates per slice
#define TILES (CPS / 128)    // 8 tiles per block
#define IMAX 0x7fffffff

typedef __attribute__((ext_vector_type(8))) short bf16x8;  // 8 bf16 (4 VGPRs)
typedef __attribute__((ext_vector_type(4))) float f32x4;
typedef unsigned int u32;
typedef unsigned short u16;

static __device__ __forceinline__ u16 f2bf(float f) {   // RNE fp32 -> bf16
    u32 u = __float_as_uint(f);
    return (u16)((u + 0x7fffu + ((u >> 16) & 1u)) >> 16);
}

// literal-constant size/offset required by the intrinsic -> macro
#define GLOAD16(g, l, off)                                                        \
    __builtin_amdgcn_global_load_lds(                                             \
        (const __attribute__((address_space(1))) void*)(g),                       \
        (__attribute__((address_space(3))) void*)(l), 16, (off), 0)

// ---------- kernel 1: norms + normalized bf16 matrix ----------
__global__ void kprep(const float* __restrict__ emb, u16* __restrict__ ENb,
                      float* __restrict__ invn) {
    const int wid = threadIdx.x >> 6, l = threadIdx.x & 63;
    const int row = blockIdx.x * 4 + wid;
    const float4 v = *(const float4*)&emb[(size_t)row * DD + l * 4];
    float ss = v.x * v.x + v.y * v.y + v.z * v.z + v.w * v.w;
#pragma unroll
    for (int o = 1; o < 64; o <<= 1) ss += __shfl_xor(ss, o);
    const float inv = 1.0f / fmaxf(sqrtf(ss), 1e-12f);
    if (l == 0) invn[row] = inv;
    ushort4 o4;
    o4.x = f2bf(v.x * inv); o4.y = f2bf(v.y * inv);
    o4.z = f2bf(v.z * inv); o4.w = f2bf(v.w * inv);
    *(ushort4*)&ENb[(size_t)row * DD + l * 4] = o4;
}

// ---------- kernel 2: first two indices of each class -> posidx ----------
static __device__ __forceinline__ void comb2(int& a1, int& a2, int b1, int b2) {
    const int lo = min(a1, b1);
    const int hi = max(a1, b1);
    a2 = min(hi, min(a2, b2));
    a1 = lo;
}

__global__ void kclass(const int* __restrict__ labels, int* __restrict__ posidx) {
    const int c = blockIdx.x;       // one block per class
    const int tid = threadIdx.x;    // 256
    int m1 = IMAX, m2 = IMAX;
    for (int j = tid; j < NN; j += 256) {   // ascending -> m1 < m2 per thread
        if (labels[j] == c) {
            if (m1 == IMAX) m1 = j;
            else if (m2 == IMAX) m2 = j;
        }
    }
#pragma unroll
    for (int o = 1; o < 64; o <<= 1)
        comb2(m1, m2, __shfl_xor(m1, o), __shfl_xor(m2, o));
    __shared__ int s1[4], s2[4];
    __shared__ int bj1, bj2;
    const int wave = tid >> 6, lane = tid & 63;
    if (lane == 0) { s1[wave] = m1; s2[wave] = m2; }
    __syncthreads();
    if (tid == 0) {
        comb2(m1, m2, s1[1], s2[1]);
        comb2(m1, m2, s1[2], s2[2]);
        comb2(m1, m2, s1[3], s2[3]);
        bj1 = m1; bj2 = m2;
    }
    __syncthreads();
    const int j1 = bj1, j2 = bj2;
    for (int j = tid; j < NN; j += 256)     // every j has exactly one class
        if (labels[j] == c) posidx[j] = (j2 == IMAX) ? -1 : ((j == j1) ? j2 : j1);
}

// ---------- kernel 3: exact fp32 d_ap ----------
__global__ void kdap(const float* __restrict__ emb, const float* __restrict__ invn,
                     const int* __restrict__ posidx, float* __restrict__ dap) {
    const int wid = threadIdx.x >> 6, l = threadIdx.x & 63;
    const int i = blockIdx.x * 4 + wid;
    const int p = posidx[i];
    float dv = 0.0f;
    if (p >= 0) {   // uniform per wave
        const float4 a = *(const float4*)&emb[(size_t)i * DD + l * 4];
        const float4 b = *(const float4*)&emb[(size_t)p * DD + l * 4];
        float s = a.x * b.x + a.y * b.y + a.z * b.z + a.w * b.w;
#pragma unroll
        for (int o = 1; o < 64; o <<= 1) s += __shfl_xor(s, o);
        const float sim = s * invn[i] * invn[p];
        dv = fminf(fmaxf(1.0f - sim, 0.0f), 2.0f);
    }
    if (l == 0) dap[i] = dv;
}

// ---------- kernel 4: MFMA mining ----------
// R3's proven layout (BK=64, 128B LDS rows, XOR chunk swizzle, conflict-free)
// with ONE change: counted s_waitcnt vmcnt(8) + raw s_barrier instead of the
// vmcnt(0)-draining __syncthreads -> staging stays in flight across barriers.
__global__ __launch_bounds__(256) void kmine(
    const u16* __restrict__ ENb, const int* __restrict__ labels,
    const float* __restrict__ dap, float* __restrict__ pM1, float* __restrict__ pMN)
{
    __shared__ __align__(16) u16 As0[128 * 64], As1[128 * 64];   // 16 KB each
    __shared__ __align__(16) u16 Bs0[128 * 64], Bs1[128 * 64];
    __shared__ __align__(16) int Ls[CPS];                        // candidate labels
    __shared__ float RedN[2][128], RedS[2][128];

    const int tid = threadIdx.x;
    const int l = tid & 63;
    const int wid = tid >> 6;
    const int wr = wid >> 1;      // candidate half (M)
    const int wc = wid & 1;       // anchor half (N)
    const int slice = blockIdx.x;
    const int a0 = blockIdx.y * 128;

    const int frow = l & 15;      // row within 16x16 subtile
    const int fq = l >> 4;        // k-quarter 0..3
    const int fj = l & 7;         // row&7 for swizzle
    const int lch = (tid & 7) ^ ((tid >> 3) & 7);   // swizzled source chunk

    // --- prologue register loads (outside the loop's vmcnt ledger) ---
    const int4 lv = *(const int4*)&labels[slice * CPS + tid * 4];
    int la[4]; float hiv[4];
#pragma unroll
    for (int n = 0; n < 4; ++n) {
        const int ai = a0 + wc * 64 + n * 16 + frow;
        la[n] = labels[ai];
        hiv[n] = 1.0f - dap[ai];
    }
    *(int4*)&Ls[tid * 4] = lv;

    // staged-source pointers: 8 threads x 16B = 128B contiguous per row
    const char* ENc = (const char*)ENb;
    const char* ag[4]; const char* bg[4];
#pragma unroll
    for (int sub = 0; sub < 4; ++sub) {
        ag[sub] = ENc + (size_t)(slice * CPS + (tid >> 3) + 32 * sub) * 512 + lch * 16;
        bg[sub] = ENc + (size_t)(a0        + (tid >> 3) + 32 * sub) * 512 + lch * 16;
    }

    // one step = 8 DMAs (4 A-rows-groups + 4 B): BK=64 chunk, 16 KB each of A,B
#define STAGE(ABUF, BBUF, OFF) do {                                               \
        _Pragma("unroll")                                                         \
        for (int sub = 0; sub < 4; ++sub)                                         \
            GLOAD16(ag[sub], &ABUF[tid * 8 + sub * 2048], OFF);                   \
        _Pragma("unroll")                                                         \
        for (int sub = 0; sub < 4; ++sub)                                         \
            GLOAD16(bg[sub], &BBUF[tid * 8 + sub * 2048], OFF);                   \
    } while (0)

#define COMPUTE(RA, RB, FIRST) do {                                               \
        _Pragma("unroll")                                                         \
        for (int h = 0; h < 2; ++h) {                                             \
            bf16x8 af[4], bf[4];                                                  \
            const int p = ((4 * h + fq) ^ fj) * 8;                                \
            _Pragma("unroll")                                                     \
            for (int m = 0; m < 4; ++m)                                           \
                af[m] = *(const bf16x8*)&RA[(wr * 64 + m * 16 + frow) * 64 + p];  \
            _Pragma("unroll")                                                     \
            for (int n = 0; n < 4; ++n)                                           \
                bf[n] = *(const bf16x8*)&RB[(wc * 64 + n * 16 + frow) * 64 + p];  \
            __builtin_amdgcn_s_setprio(1);                                        \
            _Pragma("unroll")                                                     \
            for (int m = 0; m < 4; ++m)                                           \
                _Pragma("unroll")                                                 \
                for (int n = 0; n < 4; ++n)                                       \
                    acc[m][n] = __builtin_amdgcn_mfma_f32_16x16x32_bf16(          \
                        af[m], bf[n], ((FIRST) && h == 0) ? Zv : acc[m][n],       \
                        0, 0, 0);                                                 \
            __builtin_amdgcn_s_setprio(0);                                        \
        }                                                                         \
    } while (0)

    float mN[4], m1[4];
#pragma unroll
    for (int n = 0; n < 4; ++n) { mN[n] = -INFINITY; m1[n] = -INFINITY; }
    const f32x4 Zv = {0.f, 0.f, 0.f, 0.f};
    f32x4 acc[4][4];

    // prologue: stage tile0/kc0, make labels visible
    STAGE(As0, Bs0, 0);
    asm volatile("s_waitcnt lgkmcnt(0)" ::: "memory");
    __builtin_amdgcn_s_barrier();

    for (int t = 0; t < TILES; ++t) {
        // sk=0: stage kc1 -> buf1; compute buf0 (kc0, fresh acc)
        STAGE(As1, Bs1, 128);
        asm volatile("s_waitcnt vmcnt(8)" ::: "memory");
        __builtin_amdgcn_s_barrier();
        COMPUTE(As0, Bs0, true);
        __builtin_amdgcn_s_barrier();
        // sk=1: stage kc2 -> buf0; compute buf1 (kc1)
        STAGE(As0, Bs0, 256);
        asm volatile("s_waitcnt vmcnt(8)" ::: "memory");
        __builtin_amdgcn_s_barrier();
        COMPUTE(As1, Bs1, false);
        __builtin_amdgcn_s_barrier();
        // sk=2: stage kc3 -> buf1; compute buf0 (kc2)
        STAGE(As1, Bs1, 384);
        asm volatile("s_waitcnt vmcnt(8)" ::: "memory");
        __builtin_amdgcn_s_barrier();
        COMPUTE(As0, Bs0, false);
        __builtin_amdgcn_s_barrier();
        // sk=3: stage next tile kc0 -> buf0; compute buf1 (kc3); epilogue
        if (t < TILES - 1) {
#pragma unroll
            for (int sub = 0; sub < 4; ++sub) ag[sub] += 65536;   // +128 rows
            STAGE(As0, Bs0, 0);
            asm volatile("s_waitcnt vmcnt(8)" ::: "memory");
        } else {
            asm volatile("s_waitcnt vmcnt(0)" ::: "memory");
        }
        __builtin_amdgcn_s_barrier();
        COMPUTE(As1, Bs1, false);
        {   // tile epilogue: mask + running maxes (acc re-seeded by FIRST next tile)
            int lcv[16];
#pragma unroll
            for (int m = 0; m < 4; ++m) {
                const int4 v = *(const int4*)&Ls[t * 128 + wr * 64 + m * 16 + fq * 4];
                lcv[m * 4 + 0] = v.x; lcv[m * 4 + 1] = v.y;
                lcv[m * 4 + 2] = v.z; lcv[m * 4 + 3] = v.w;
            }
#pragma unroll
            for (int n = 0; n < 4; ++n) {
#pragma unroll
                for (int m = 0; m < 4; ++m)
#pragma unroll
                    for (int r = 0; r < 4; ++r) {
                        const float sv = acc[m][n][r];
                        const float sel = (lcv[m * 4 + r] != la[n]) ? sv : -INFINITY;
                        mN[n] = fmaxf(mN[n], sel);
                        m1[n] = fmaxf(m1[n], (sel < hiv[n]) ? sel : -INFINITY);
                    }
            }
        }
        __builtin_amdgcn_s_barrier();
    }
#undef STAGE
#undef COMPUTE

    // reduce the 4 candidate row-groups (lanes l, l^16, l^32, l^48 share anchor)
#pragma unroll
    for (int n = 0; n < 4; ++n) {
        mN[n] = fmaxf(mN[n], __shfl_xor(mN[n], 16));
        mN[n] = fmaxf(mN[n], __shfl_xor(mN[n], 32));
        m1[n] = fmaxf(m1[n], __shfl_xor(m1[n], 16));
        m1[n] = fmaxf(m1[n], __shfl_xor(m1[n], 32));
    }
    if (fq == 0) {
#pragma unroll
        for (int n = 0; n < 4; ++n) {
            RedN[wr][wc * 64 + n * 16 + frow] = mN[n];
            RedS[wr][wc * 64 + n * 16 + frow] = m1[n];
        }
    }
    __syncthreads();
    if (tid < 128) {   // combine the two candidate halves, write partials
        pMN[slice * NN + a0 + tid] = fmaxf(RedN[0][tid], RedN[1][tid]);
        pM1[slice * NN + a0 + tid] = fmaxf(RedS[0][tid], RedS[1][tid]);
    }
}

// ---------- kernel 5: combine slices -> per-block partial sums ----------
__global__ void kcombine(const int* __restrict__ posidx, const float* __restrict__ dap,
                         const float* __restrict__ pM1, const float* __restrict__ pMN,
                         float* __restrict__ partials)
{
    const int i = blockIdx.x * 256 + threadIdx.x;
    float loss = 0.0f, cnt = 0.0f;
    if (posidx[i] >= 0) {
        float s1 = -INFINITY, sN = -INFINITY;
#pragma unroll
        for (int s = 0; s < SL; ++s) {
            s1 = fmaxf(s1, pM1[s * NN + i]);
            sN = fmaxf(sN, pMN[s * NN + i]);
        }
        const float da = dap[i];
        const float lo = 1.0f - da - MARGIN;
        const float M = (s1 > lo) ? s1 : sN;   // has_semi ? best semi : hardest
        const float dan = fminf(fmaxf(1.0f - M, 0.0f), 2.0f);
        loss = fmaxf(da - dan + MARGIN, 0.0f);
        cnt = 1.0f;
    }
#pragma unroll
    for (int off = 1; off < 64; off <<= 1) {
        loss += __shfl_xor(loss, off);
        cnt  += __shfl_xor(cnt, off);
    }
    __shared__ float sl[4], sc[4];
    const int wave = threadIdx.x >> 6, lane = threadIdx.x & 63;
    if (lane == 0) { sl[wave] = loss; sc[wave] = cnt; }
    __syncthreads();
    if (threadIdx.x == 0) {
        partials[blockIdx.x]      = sl[0] + sl[1] + sl[2] + sl[3];
        partials[32 + blockIdx.x] = sc[0] + sc[1] + sc[2] + sc[3];
    }
}

// ---------- kernel 6: final scalar ----------
__global__ void kfinal(const float* __restrict__ partials, float* __restrict__ out) {
    const int t = threadIdx.x;  // 64
    float L = (t < 32) ? partials[t] : 0.0f;
    float C = (t < 32) ? partials[32 + t] : 0.0f;
#pragma unroll
    for (int off = 1; off < 64; off <<= 1) {
        L += __shfl_xor(L, off);
        C += __shfl_xor(C, off);
    }
    if (t == 0) out[0] = (C > 0.0f) ? (L / C) : 0.0f;
}

extern "C" void kernel_launch(void* const* d_in, const int* in_sizes, int n_in,
                              void* d_out, int out_size, void* d_ws, size_t ws_size,
                              hipStream_t stream) {
    const float* emb  = (const float*)d_in[0];
    const int* labels = (const int*)d_in[1];
    float* out = (float*)d_out;

    char* w = (char*)d_ws;
    u16*   ENb  = (u16*)w;                       w += (size_t)NN * DD * 2;   // 4 MB
    float* invn = (float*)w;                     w += NN * 4;
    float* dapv = (float*)w;                     w += NN * 4;
    int*   posi = (int*)w;                       w += NN * 4;
    float* pM1  = (float*)w;                     w += (size_t)SL * NN * 4;   // 256 KB
    float* pMN  = (float*)w;                     w += (size_t)SL * NN * 4;   // 256 KB
    float* parts = (float*)w;

    kprep<<<NN / 4, 256, 0, stream>>>(emb, ENb, invn);
    kclass<<<128, 256, 0, stream>>>(labels, posi);
    kdap<<<NN / 4, 256, 0, stream>>>(emb, invn, posi, dapv);
    kmine<<<dim3(SL, NN / 128), 256, 0, stream>>>(ENb, labels, dapv, pM1, pMN);
    kcombine<<<NN / 256, 256, 0, stream>>>(posi, dapv, pM1, pMN, parts);
    kfinal<<<1, 64, 0, stream>>>(parts, out);
}